// Round 3
// baseline (515.339 us; speedup 1.0000x reference)
//
#include <hip/hip_runtime.h>

typedef __attribute__((ext_vector_type(4))) float float4v;

__device__ __forceinline__ void getC(int st, float C[4]) {
    C[0] = 1.f; C[1] = 0.f; C[2] = 0.f; C[3] = 0.f;
    if (st == 4)      { C[0] = 1.125f;          C[1] = -1.f / 24.f; }
    else if (st == 6) { C[0] = 75.f / 64.f;     C[1] = -25.f / 384.f;
                        C[2] = 3.f / 640.f; }
    else if (st == 8) { C[0] = 1225.f / 1024.f; C[1] = -245.f / 3072.f;
                        C[2] = 49.f / 5120.f;   C[3] = -5.f / 7168.f; }
}

__device__ __forceinline__ void ld8(const float* __restrict__ p, float o[8]) {
    float4v a = *(const float4v*)p;
    float4v b = *(const float4v*)(p + 4);
    o[0] = a.x; o[1] = a.y; o[2] = a.z; o[3] = a.w;
    o[4] = b.x; o[5] = b.y; o[6] = b.z; o[7] = b.w;
}
__device__ __forceinline__ void st8(float* __restrict__ p, const float o[8]) {
    float4v a = { o[0], o[1], o[2], o[3] };
    float4v b = { o[4], o[5], o[6], o[7] };
    *(float4v*)p       = a;
    *(float4v*)(p + 4) = b;
}

// ---------------- Kernel 1: update_E ----------------
// diff1:  d[i] = sum_k c_k (a[i+k-1] - a[i-k]) * rd   (zero-padded)
// m_Hz_x' = bx*m_Hz_x + ax*dHz_dx ; m_Hx_z' = by*m_Hx_z + ay*dHx_dz
// Ey' = ca*Ey + cb*((dHz_dx/kx + m_Hz_x') - (dHx_dz/ky + m_Hx_z'))
__global__ __launch_bounds__(256) void k1_updateE(
    const float* __restrict__ ca, const float* __restrict__ cb,
    const float* __restrict__ Ey, const float* __restrict__ Hx,
    const float* __restrict__ Hz,
    const float* __restrict__ mHxz, const float* __restrict__ mHzx,
    const float* __restrict__ ky, const float* __restrict__ ay,
    const float* __restrict__ by,
    const float* __restrict__ kx, const float* __restrict__ ax,
    const float* __restrict__ bx,
    const float* __restrict__ rdyp, const float* __restrict__ rdxp,
    const int* __restrict__ stp,
    float* __restrict__ outEy, float* __restrict__ outMHxz,
    float* __restrict__ outMHzx,
    int B, int NY, int NX)
{
    constexpr int EPT = 8;
    const int y = blockIdx.x, b = blockIdx.y;
    const int x0 = (int)threadIdx.x * EPT;
    const size_t row  = ((size_t)b * NY + y) * (size_t)NX;
    const size_t crow = (size_t)y * (size_t)NX;

    const float rdx = rdxp[0];
    const float rdy = rdyp[0];
    int ns = stp[0] >> 1;
    if (ns < 1) ns = 1; if (ns > 4) ns = 4;
    float C[4]; getC(ns * 2, C);

    // Hz register window: w[j] = Hz[b,y,x0-4+j], taps j = 0..14
    float w[16];
    {
        ld8(Hz + row + x0, &w[4]);
        #pragma unroll
        for (int j = 0; j < 4; ++j) {
            const int x = x0 - 4 + j;
            w[j] = (x >= 0 && j >= 4 - ns) ? Hz[row + x] : 0.f;
        }
        #pragma unroll
        for (int j = 12; j < 15; ++j) {
            const int x = x0 - 4 + j;
            w[j] = (x < NX && j <= 10 + ns) ? Hz[row + x] : 0.f;
        }
        w[15] = 0.f;
    }

    float dHzdx[EPT], dHxdz[EPT];
    #pragma unroll
    for (int i = 0; i < EPT; ++i) { dHzdx[i] = 0.f; dHxdz[i] = 0.f; }

    #pragma unroll
    for (int k = 1; k <= 4; ++k) {
        if (k <= ns) {
            const float ck = C[k - 1];
            #pragma unroll
            for (int i = 0; i < EPT; ++i)
                dHzdx[i] += ck * (w[i + 4 + k - 1] - w[i + 4 - k]);

            const int yp = y + k - 1, ym = y - k;
            float up[EPT], dn[EPT];
            if (yp < NY) {
                ld8(Hx + ((size_t)b * NY + yp) * (size_t)NX + x0, up);
            } else {
                #pragma unroll
                for (int i = 0; i < EPT; ++i) up[i] = 0.f;
            }
            if (ym >= 0) {
                ld8(Hx + ((size_t)b * NY + ym) * (size_t)NX + x0, dn);
            } else {
                #pragma unroll
                for (int i = 0; i < EPT; ++i) dn[i] = 0.f;
            }
            #pragma unroll
            for (int i = 0; i < EPT; ++i) dHxdz[i] += ck * (up[i] - dn[i]);
        }
    }

    float eyv[EPT], mzxv[EPT], mxzv[EPT], cav[EPT], cbv[EPT];
    float kxv[EPT], axv[EPT], bxv[EPT];
    ld8(Ey   + row + x0, eyv);
    ld8(mHzx + row + x0, mzxv);
    ld8(mHxz + row + x0, mxzv);
    ld8(ca + crow + x0, cav);
    ld8(cb + crow + x0, cbv);
    ld8(kx + x0, kxv);
    ld8(ax + x0, axv);
    ld8(bx + x0, bxv);
    const float kyv = ky[y];
    const float ayv = ay[y];
    const float byv = by[y];

    float oE[EPT], oMxz[EPT], oMzx[EPT];
    #pragma unroll
    for (int i = 0; i < EPT; ++i) {
        const float dzx = dHzdx[i] * rdx;              // dHz_dx
        const float dxz = dHxdz[i] * rdy;              // dHx_dz
        const float mzx_n = bxv[i] * mzxv[i] + axv[i] * dzx;
        const float mxz_n = byv * mxzv[i] + ayv * dxz;
        const float ey_n = cav[i] * eyv[i]
            + cbv[i] * ((dzx / kxv[i] + mzx_n) - (dxz / kyv + mxz_n));
        oE[i]   = ey_n;
        oMxz[i] = mxz_n;
        oMzx[i] = mzx_n;
    }
    st8(outEy   + row + x0, oE);
    st8(outMHxz + row + x0, oMxz);
    st8(outMHzx + row + x0, oMzx);
}

// ---------------- Kernel 2: update_H ----------------
// diffh1: d[i] = sum_k c_k (a[i+k] - a[i-k+1]) * rd  (zero-padded), on NEW Ey
__global__ __launch_bounds__(256) void k2_updateH(
    const float* __restrict__ cq,
    const float* __restrict__ Hx, const float* __restrict__ Hz,
    const float* __restrict__ mEyx, const float* __restrict__ mEyz,
    const float* __restrict__ kyh, const float* __restrict__ ayh,
    const float* __restrict__ byh,
    const float* __restrict__ kxh, const float* __restrict__ axh,
    const float* __restrict__ bxh,
    const float* __restrict__ rdyp, const float* __restrict__ rdxp,
    const int* __restrict__ stp,
    const float* __restrict__ newEy,
    float* __restrict__ outHx, float* __restrict__ outHz,
    float* __restrict__ outMEyx, float* __restrict__ outMEyz,
    int B, int NY, int NX)
{
    constexpr int EPT = 8;
    const int y = blockIdx.x, b = blockIdx.y;
    const int x0 = (int)threadIdx.x * EPT;
    const size_t row  = ((size_t)b * NY + y) * (size_t)NX;
    const size_t crow = (size_t)y * (size_t)NX;

    const float rdx = rdxp[0];
    const float rdy = rdyp[0];
    int ns = stp[0] >> 1;
    if (ns < 1) ns = 1; if (ns > 4) ns = 4;
    float C[4]; getC(ns * 2, C);

    // Ey' register window: w[j] = Ey'[b,y,x0-4+j], taps j = 1..15
    float w[16];
    w[0] = 0.f;
    {
        ld8(newEy + row + x0, &w[4]);
        #pragma unroll
        for (int j = 1; j < 4; ++j) {
            const int x = x0 - 4 + j;
            w[j] = (x >= 0 && j >= 5 - ns) ? newEy[row + x] : 0.f;
        }
        #pragma unroll
        for (int j = 12; j < 16; ++j) {
            const int x = x0 - 4 + j;
            w[j] = (x < NX && j <= 11 + ns) ? newEy[row + x] : 0.f;
        }
    }

    float dEdx[EPT], dEdz[EPT];
    #pragma unroll
    for (int i = 0; i < EPT; ++i) { dEdx[i] = 0.f; dEdz[i] = 0.f; }

    #pragma unroll
    for (int k = 1; k <= 4; ++k) {
        if (k <= ns) {
            const float ck = C[k - 1];
            #pragma unroll
            for (int i = 0; i < EPT; ++i)
                dEdx[i] += ck * (w[i + 4 + k] - w[i + 5 - k]);

            const int yp = y + k, ym = y + 1 - k;
            float up[EPT], dn[EPT];
            if (yp < NY) {
                ld8(newEy + ((size_t)b * NY + yp) * (size_t)NX + x0, up);
            } else {
                #pragma unroll
                for (int i = 0; i < EPT; ++i) up[i] = 0.f;
            }
            if (k == 1) {
                #pragma unroll
                for (int i = 0; i < EPT; ++i) dn[i] = w[4 + i];   // ym == y
            } else if (ym >= 0) {
                ld8(newEy + ((size_t)b * NY + ym) * (size_t)NX + x0, dn);
            } else {
                #pragma unroll
                for (int i = 0; i < EPT; ++i) dn[i] = 0.f;
            }
            #pragma unroll
            for (int i = 0; i < EPT; ++i) dEdz[i] += ck * (up[i] - dn[i]);
        }
    }

    float hxv[EPT], hzv[EPT], mxv[EPT], mzv[EPT], cqv[EPT];
    float kxhv[EPT], axhv[EPT], bxhv[EPT];
    ld8(Hx   + row + x0, hxv);
    ld8(Hz   + row + x0, hzv);
    ld8(mEyx + row + x0, mxv);
    ld8(mEyz + row + x0, mzv);
    ld8(cq + crow + x0, cqv);
    ld8(kxh + x0, kxhv);
    ld8(axh + x0, axhv);
    ld8(bxh + x0, bxhv);
    const float kyhv = kyh[y];
    const float ayhv = ayh[y];
    const float byhv = byh[y];

    float oHx[EPT], oHz[EPT], oMx[EPT], oMz[EPT];
    #pragma unroll
    for (int i = 0; i < EPT; ++i) {
        const float dz = dEdz[i] * rdy;            // dEy_dz
        const float dx = dEdx[i] * rdx;            // dEy_dx
        const float mz_n = byhv * mzv[i] + ayhv * dz;
        const float mx_n = bxhv[i] * mxv[i] + axhv[i] * dx;
        const float cqf = cqv[i];
        oHx[i] = hxv[i] - cqf * (dz / kyhv + mz_n);
        oHz[i] = hzv[i] + cqf * (dx / kxhv[i] + mx_n);
        oMx[i] = mx_n;
        oMz[i] = mz_n;
    }
    st8(outHx   + row + x0, oHx);
    st8(outHz   + row + x0, oHz);
    st8(outMEyx + row + x0, oMx);
    st8(outMEyz + row + x0, oMz);
}

extern "C" void kernel_launch(void* const* d_in, const int* in_sizes, int n_in,
                              void* d_out, int out_size, void* d_ws, size_t ws_size,
                              hipStream_t stream)
{
    const float* ca   = (const float*)d_in[0];
    const float* cb   = (const float*)d_in[1];
    const float* cq   = (const float*)d_in[2];
    const float* Ey   = (const float*)d_in[3];
    const float* Hx   = (const float*)d_in[4];
    const float* Hz   = (const float*)d_in[5];
    const float* mHxz = (const float*)d_in[6];
    const float* mHzx = (const float*)d_in[7];
    const float* mEyx = (const float*)d_in[8];
    const float* mEyz = (const float*)d_in[9];
    const float* ky   = (const float*)d_in[10];
    const float* kyh  = (const float*)d_in[11];
    const float* ay   = (const float*)d_in[12];
    const float* ayh  = (const float*)d_in[13];
    const float* by   = (const float*)d_in[14];
    const float* byh  = (const float*)d_in[15];
    const float* kx   = (const float*)d_in[16];
    const float* kxh  = (const float*)d_in[17];
    const float* ax   = (const float*)d_in[18];
    const float* axh  = (const float*)d_in[19];
    const float* bx   = (const float*)d_in[20];
    const float* bxh  = (const float*)d_in[21];
    const float* rdy  = (const float*)d_in[22];
    const float* rdx  = (const float*)d_in[23];
    const int* stp    = (const int*)d_in[24];

    const int NX   = in_sizes[16];
    const int NYNX = in_sizes[0];
    const int NY   = NYNX / NX;
    const int B    = in_sizes[3] / NYNX;
    const size_t plane = (size_t)B * (size_t)NYNX;

    float* out     = (float*)d_out;
    float* outEy   = out;
    float* outHx   = out + 1 * plane;
    float* outHz   = out + 2 * plane;
    float* outMHxz = out + 3 * plane;
    float* outMHzx = out + 4 * plane;
    float* outMEyx = out + 5 * plane;
    float* outMEyz = out + 6 * plane;

    dim3 grid(NY, B);
    dim3 block(NX / 8);

    k1_updateE<<<grid, block, 0, stream>>>(
        ca, cb, Ey, Hx, Hz, mHxz, mHzx, ky, ay, by, kx, ax, bx,
        rdy, rdx, stp, outEy, outMHxz, outMHzx, B, NY, NX);

    k2_updateH<<<grid, block, 0, stream>>>(
        cq, Hx, Hz, mEyx, mEyz, kyh, ayh, byh, kxh, axh, bxh,
        rdy, rdx, stp, outEy, outHx, outHz, outMEyx, outMEyz,
        B, NY, NX);
}